// Round 1
// baseline (552.234 us; speedup 1.0000x reference)
//
#include <hip/hip_runtime.h>

typedef __bf16 bf16_t;
typedef __bf16 bf16x8 __attribute__((ext_vector_type(8)));
typedef __bf16 bf16x4 __attribute__((ext_vector_type(4)));
typedef float f32x4 __attribute__((ext_vector_type(4)));

#define SEQL 2048
#define DIMM 4096
#define NH 32
#define NKV 8
#define HD 128

__device__ __forceinline__ void gl2lds16(const void* g, void* l) {
  __builtin_amdgcn_global_load_lds((__attribute__((address_space(1))) void*)g,
                                   (__attribute__((address_space(3))) void*)l,
                                   16, 0, 0);
}

// ---------------- fused fp32 -> bf16 convert of all 5 tensors ----------------
// dst is one contiguous region: [x (8388608)][wq (16777216)][wk (4194304)][wv (4194304)][wo (16777216)]
__global__ __launch_bounds__(256) void cvt5_kernel(const float* __restrict__ s0,
                                                   const float* __restrict__ s1,
                                                   const float* __restrict__ s2,
                                                   const float* __restrict__ s3,
                                                   const float* __restrict__ s4,
                                                   bf16_t* __restrict__ dst) {
  long i4 = (long)blockIdx.x * 256 + threadIdx.x;
  long e = i4 * 4;
  const float* s;
  long o;
  if (e < 8388608L)       { s = s0; o = e; }
  else if (e < 25165824L) { s = s1; o = e - 8388608L; }
  else if (e < 29360128L) { s = s2; o = e - 25165824L; }
  else if (e < 33554432L) { s = s3; o = e - 29360128L; }
  else                    { s = s4; o = e - 33554432L; }
  float4 v = *(const float4*)(s + o);
  bf16x4 ov;
  ov[0] = (bf16_t)v.x; ov[1] = (bf16_t)v.y; ov[2] = (bf16_t)v.z; ov[3] = (bf16_t)v.w;
  *(bf16x4*)(dst + e) = ov;
}

// ---------------- NT GEMM: C[M,N] = A[M,K] * B[N,K]^T (bf16 in, fp32 out) ----
// 128x128 tile, BK=32, 256 threads (4 waves, 2x2 of 64x64), 16x16x32 MFMA.
__global__ __launch_bounds__(256) void gemm_bt_kernel(const bf16_t* __restrict__ A,
                                                      const bf16_t* __restrict__ B,
                                                      float* __restrict__ C,
                                                      int M, int N, int K) {
  __shared__ bf16_t lA[128 * 32];
  __shared__ bf16_t lB[128 * 32];
  const int tid = threadIdx.x;
  const int bm = blockIdx.y * 128, bn = blockIdx.x * 128;
  const int lane = tid & 63, wave = tid >> 6;
  const int wm = (wave >> 1) * 64, wn = (wave & 1) * 64;
  const int lr = lane & 15, quad = lane >> 4;

  f32x4 acc[4][4];
#pragma unroll
  for (int mi = 0; mi < 4; ++mi)
#pragma unroll
    for (int ni = 0; ni < 4; ++ni)
      acc[mi][ni] = (f32x4){0.f, 0.f, 0.f, 0.f};

  const int i0 = tid, i1 = tid + 256;
  const bf16_t* Abase = A + (long)bm * K;
  const bf16_t* Bbase = B + (long)bn * K;
  const long off0 = (long)(i0 >> 2) * K + (i0 & 3) * 8;
  const long off1 = (long)(i1 >> 2) * K + (i1 & 3) * 8;

  for (int k0 = 0; k0 < K; k0 += 32) {
    __syncthreads();
    gl2lds16(Abase + off0 + k0, lA + i0 * 8);
    gl2lds16(Abase + off1 + k0, lA + i1 * 8);
    gl2lds16(Bbase + off0 + k0, lB + i0 * 8);
    gl2lds16(Bbase + off1 + k0, lB + i1 * 8);
    __syncthreads();
    bf16x8 af[4], bfr[4];
#pragma unroll
    for (int mi = 0; mi < 4; ++mi)
      af[mi] = *(const bf16x8*)&lA[(wm + mi * 16 + lr) * 32 + quad * 8];
#pragma unroll
    for (int ni = 0; ni < 4; ++ni)
      bfr[ni] = *(const bf16x8*)&lB[(wn + ni * 16 + lr) * 32 + quad * 8];
#pragma unroll
    for (int mi = 0; mi < 4; ++mi)
#pragma unroll
      for (int ni = 0; ni < 4; ++ni)
        acc[mi][ni] = __builtin_amdgcn_mfma_f32_16x16x32_bf16(af[mi], bfr[ni], acc[mi][ni], 0, 0, 0);
  }

#pragma unroll
  for (int mi = 0; mi < 4; ++mi) {
    const int row = bm + wm + mi * 16 + quad * 4;
#pragma unroll
    for (int ni = 0; ni < 4; ++ni) {
      const int col = bn + wn + ni * 16 + lr;
      float* cp = C + (long)row * N + col;
#pragma unroll
      for (int r = 0; r < 4; ++r) cp[(long)r * N] = acc[mi][ni][r];
    }
  }
}

// ---------------- fused per-head RMSNorm + RoPE, fp32 -> bf16, [s][h*128] -> [h][s][128]
__global__ __launch_bounds__(256) void rmsrope_kernel(const float* __restrict__ xf, // + col offset
                                                      int rstride,
                                                      const float* __restrict__ nw,
                                                      const float* __restrict__ rope,
                                                      const int* __restrict__ pos,
                                                      bf16_t* __restrict__ out,
                                                      int H) {
  const int wave = threadIdx.x >> 6, lane = threadIdx.x & 63;
  const int flat = blockIdx.x * 4 + wave;
  const int s = flat / H, h = flat - s * H;
  const float* xp = xf + (long)s * rstride + h * HD;
  float x1 = xp[lane], x2 = xp[lane + 64];
  float ss = x1 * x1 + x2 * x2;
#pragma unroll
  for (int off = 32; off > 0; off >>= 1) ss += __shfl_xor(ss, off, 64);
  const float sc = rsqrtf(ss * (1.0f / 128.0f) + 1e-6f);
  const float n1 = x1 * sc * nw[lane];
  const float n2 = x2 * sc * nw[lane + 64];
  const int p = pos[s];
  const float c = rope[p * 128 + lane * 2];
  const float sn = rope[p * 128 + lane * 2 + 1];
  bf16_t* op = out + ((long)h * SEQL + s) * HD;
  op[lane] = (bf16_t)(n1 * c - n2 * sn);
  op[lane + 64] = (bf16_t)(n2 * c + n1 * sn);
}

// ---------------- V transpose: fp32 [s][(col off)+hk*128+d] -> bf16 [hk][d][s] ----
__global__ __launch_bounds__(256) void vtrans_kernel(const float* __restrict__ vf, // + col offset
                                                     int rstride,
                                                     bf16_t* __restrict__ vb) {
  __shared__ bf16_t lt[128 * 129];
  const int hk = blockIdx.x >> 4;
  const int s0 = (blockIdx.x & 15) * 128;
  const int t = threadIdx.x;
  for (int i = t; i < 128 * 128; i += 256) {
    const int sl = i >> 7, d = i & 127;
    lt[sl * 129 + d] = (bf16_t)vf[(long)(s0 + sl) * rstride + hk * HD + d];
  }
  __syncthreads();
#pragma unroll
  for (int cc = 0; cc < 8; ++cc) {
    const int cidx = t + 256 * cc;
    const int d = cidx >> 4, sc = (cidx & 15) * 8;
    bf16x8 v;
#pragma unroll
    for (int j = 0; j < 8; ++j) v[j] = lt[(sc + j) * 129 + d];
    *(bf16x8*)(vb + ((long)hk * HD + d) * SEQL + s0 + sc) = v;
  }
}

// ---------------- flash attention, block-diag causal (4 segments of 512) ----
// Q [32][2048][128], K [8][2048][128], V [8][128][2048] (all bf16), O bf16 [2048][4096]
#define CK 64
#define PSTR 72
__global__ __launch_bounds__(256) void attn_kernel(const bf16_t* __restrict__ Q,
                                                   const bf16_t* __restrict__ Kt,
                                                   const bf16_t* __restrict__ Vt,
                                                   bf16_t* __restrict__ O) {
  __shared__ bf16_t lK[CK * 128];    // [kk][d]
  __shared__ bf16_t lV[128 * CK];    // [d][kk]
  __shared__ bf16_t lP[128 * PSTR];  // [m][kk]
  const int qb = blockIdx.x, g = blockIdx.y, h = blockIdx.z;
  const int hk = h >> 2;
  const int tid = threadIdx.x, lane = tid & 63, wave = tid >> 6;
  const int lr = lane & 15, quad = lane >> 4;
  const int s_base = g * 512 + qb * 128;

  bf16x8 qf[2][4];
  const bf16_t* Qp = Q + ((long)h * SEQL + s_base + wave * 32 + lr) * HD + quad * 8;
#pragma unroll
  for (int mi = 0; mi < 2; ++mi)
#pragma unroll
    for (int ks = 0; ks < 4; ++ks)
      qf[mi][ks] = *(const bf16x8*)(Qp + mi * 16 * HD + ks * 32);

  f32x4 oacc[2][8];
#pragma unroll
  for (int mi = 0; mi < 2; ++mi)
#pragma unroll
    for (int di = 0; di < 8; ++di) oacc[mi][di] = (f32x4){0.f, 0.f, 0.f, 0.f};
  float mst[2][4], lst[2][4];
#pragma unroll
  for (int mi = 0; mi < 2; ++mi)
#pragma unroll
    for (int r = 0; r < 4; ++r) { mst[mi][r] = -3.0e38f; lst[mi][r] = 0.f; }

  const float c1 = 0.08838834764831845f * 1.4426950408889634f;  // scale * log2(e)

  const int nchunk = 2 * qb + 2;
  for (int c = 0; c < nchunk; ++c) {
    __syncthreads();
    {
      const bf16_t* Kg = Kt + ((long)hk * SEQL + g * 512 + c * CK) * HD;
      const bf16_t* Vg = Vt + (long)hk * HD * SEQL + g * 512 + c * CK;
#pragma unroll
      for (int cc = 0; cc < 4; ++cc) {
        const int i = tid + 256 * cc;
        gl2lds16(Kg + (long)(i >> 4) * HD + (i & 15) * 8, lK + i * 8);
        gl2lds16(Vg + (long)(i >> 3) * SEQL + (i & 7) * 8, lV + i * 8);
      }
    }
    __syncthreads();

    f32x4 sv[2][4];
#pragma unroll
    for (int mi = 0; mi < 2; ++mi)
#pragma unroll
      for (int ni = 0; ni < 4; ++ni) sv[mi][ni] = (f32x4){0.f, 0.f, 0.f, 0.f};
#pragma unroll
    for (int ks = 0; ks < 4; ++ks) {
#pragma unroll
      for (int ni = 0; ni < 4; ++ni) {
        const bf16x8 kf = *(const bf16x8*)&lK[(ni * 16 + lr) * 128 + ks * 32 + quad * 8];
        sv[0][ni] = __builtin_amdgcn_mfma_f32_16x16x32_bf16(qf[0][ks], kf, sv[0][ni], 0, 0, 0);
        sv[1][ni] = __builtin_amdgcn_mfma_f32_16x16x32_bf16(qf[1][ks], kf, sv[1][ni], 0, 0, 0);
      }
    }

    // scale to log2 domain + causal mask (cols beyond row)
#pragma unroll
    for (int mi = 0; mi < 2; ++mi)
#pragma unroll
      for (int ni = 0; ni < 4; ++ni)
#pragma unroll
        for (int r = 0; r < 4; ++r) {
          const int colseg = c * CK + ni * 16 + lr;
          const int rowseg = qb * 128 + wave * 32 + mi * 16 + quad * 4 + r;
          const float v = sv[mi][ni][r] * c1;
          sv[mi][ni][r] = (colseg > rowseg) ? -3.0e38f : v;
        }

    // online softmax (rows live in 16-lane groups; shuffle over xor 1,2,4,8)
#pragma unroll
    for (int mi = 0; mi < 2; ++mi)
#pragma unroll
      for (int r = 0; r < 4; ++r) {
        float rm = sv[mi][0][r];
#pragma unroll
        for (int ni = 1; ni < 4; ++ni) rm = fmaxf(rm, sv[mi][ni][r]);
        rm = fmaxf(rm, __shfl_xor(rm, 1, 64));
        rm = fmaxf(rm, __shfl_xor(rm, 2, 64));
        rm = fmaxf(rm, __shfl_xor(rm, 4, 64));
        rm = fmaxf(rm, __shfl_xor(rm, 8, 64));
        const float mnew = fmaxf(mst[mi][r], rm);
        const float alpha = exp2f(mst[mi][r] - mnew);
        mst[mi][r] = mnew;
        float ps = 0.f;
#pragma unroll
        for (int ni = 0; ni < 4; ++ni) {
          const float p = exp2f(sv[mi][ni][r] - mnew);
          sv[mi][ni][r] = p;
          ps += p;
        }
        ps += __shfl_xor(ps, 1, 64);
        ps += __shfl_xor(ps, 2, 64);
        ps += __shfl_xor(ps, 4, 64);
        ps += __shfl_xor(ps, 8, 64);
        lst[mi][r] = lst[mi][r] * alpha + ps;
#pragma unroll
        for (int di = 0; di < 8; ++di) oacc[mi][di][r] *= alpha;
      }

    // P: C-layout -> LDS [m][kk] (read back in A-layout)
#pragma unroll
    for (int mi = 0; mi < 2; ++mi)
#pragma unroll
      for (int ni = 0; ni < 4; ++ni)
#pragma unroll
        for (int r = 0; r < 4; ++r)
          lP[(wave * 32 + mi * 16 + quad * 4 + r) * PSTR + ni * 16 + lr] = (bf16_t)sv[mi][ni][r];
    __syncthreads();

    // O += P @ V
#pragma unroll
    for (int ks = 0; ks < 2; ++ks) {
      const bf16x8 pf0 = *(const bf16x8*)&lP[(wave * 32 + lr) * PSTR + ks * 32 + quad * 8];
      const bf16x8 pf1 = *(const bf16x8*)&lP[(wave * 32 + 16 + lr) * PSTR + ks * 32 + quad * 8];
#pragma unroll
      for (int di = 0; di < 8; ++di) {
        const bf16x8 vfr = *(const bf16x8*)&lV[(di * 16 + lr) * CK + ks * 32 + quad * 8];
        oacc[0][di] = __builtin_amdgcn_mfma_f32_16x16x32_bf16(pf0, vfr, oacc[0][di], 0, 0, 0);
        oacc[1][di] = __builtin_amdgcn_mfma_f32_16x16x32_bf16(pf1, vfr, oacc[1][di], 0, 0, 0);
      }
    }
  }

  // epilogue: O[s][h*128+d] bf16
#pragma unroll
  for (int mi = 0; mi < 2; ++mi)
#pragma unroll
    for (int r = 0; r < 4; ++r) {
      const float inv = 1.0f / lst[mi][r];
      const int row = s_base + wave * 32 + mi * 16 + quad * 4 + r;
      bf16_t* opp = O + (long)row * DIMM + h * HD + lr;
#pragma unroll
      for (int di = 0; di < 8; ++di) opp[di * 16] = (bf16_t)(oacc[mi][di][r] * inv);
    }
}

// -----------------------------------------------------------------------------
extern "C" void kernel_launch(void* const* d_in, const int* in_sizes, int n_in,
                              void* d_out, int out_size, void* d_ws, size_t ws_size,
                              hipStream_t stream) {
  (void)in_sizes; (void)n_in; (void)out_size; (void)ws_size;
  const float* x    = (const float*)d_in[0];
  const float* wq   = (const float*)d_in[1];
  const float* wk   = (const float*)d_in[2];
  const float* wv   = (const float*)d_in[3];
  const float* wo   = (const float*)d_in[4];
  const float* qnw  = (const float*)d_in[5];
  const float* knw  = (const float*)d_in[6];
  const float* rope = (const float*)d_in[7];
  const int*   pos  = (const int*)d_in[8];
  float* out = (float*)d_out;

  char* ws = (char*)d_ws;
  size_t off = 0;
  auto alloc = [&](size_t b) { char* p = ws + off; off += (b + 255) & ~(size_t)255; return p; };
  // NOTE: first five allocations must stay contiguous (cvt5 writes them as one region)
  bf16_t* xb    = (bf16_t*)alloc((size_t)SEQL * DIMM * 2);          // 16 MiB
  bf16_t* wqkvb = (bf16_t*)alloc((size_t)DIMM * DIMM * 2);          // wq part, 32 MiB
  alloc((size_t)NKV * HD * DIMM * 2);                               // wk part (contiguous)
  alloc((size_t)NKV * HD * DIMM * 2);                               // wv part (contiguous)
  bf16_t* wob   = (bf16_t*)alloc((size_t)DIMM * DIMM * 2);          // 32 MiB
  float*  qkvf  = (float*)alloc((size_t)SEQL * 6144 * 4);           // 48 MiB
  // aliases into regions dead by the time they're written:
  bf16_t* Qb    = (bf16_t*)wqkvb;         // [32][2048][128], wqkv dead after QKV GEMM
  bf16_t* Kb    = Qb + (size_t)NH * SEQL * HD;   // [8][2048][128]
  bf16_t* Vb    = Kb + (size_t)NKV * SEQL * HD;  // [8][128][2048]
  bf16_t* attnb = xb;                     // [2048][4096], xb dead after QKV GEMM

  // 1) convert all inputs to bf16 (contiguous dst starting at xb)
  cvt5_kernel<<<dim3(49152), 256, 0, stream>>>(x, wq, wk, wv, wo, xb);
  // 2) fused QKV projection: [2048][6144] = xb @ [wq;wk;wv]^T
  gemm_bt_kernel<<<dim3(6144 / 128, SEQL / 128), 256, 0, stream>>>(xb, wqkvb, qkvf, SEQL, 6144, DIMM);
  // 3) RMSNorm + RoPE for Q and K (head-major bf16 out)
  rmsrope_kernel<<<dim3(SEQL * NH / 4), 256, 0, stream>>>(qkvf, 6144, qnw, rope, pos, Qb, NH);
  rmsrope_kernel<<<dim3(SEQL * NKV / 4), 256, 0, stream>>>(qkvf + 4096, 6144, knw, rope, pos, Kb, NKV);
  // 4) V transpose to [hk][d][s] bf16
  vtrans_kernel<<<dim3(NKV * 16), 256, 0, stream>>>(qkvf + 5120, 6144, Vb);
  // 5) attention
  attn_kernel<<<dim3(4, 4, NH), 256, 0, stream>>>(Qb, Kb, Vb, attnb);
  // 6) output projection -> fp32 d_out
  gemm_bt_kernel<<<dim3(DIMM / 128, SEQL / 128), 256, 0, stream>>>(attnb, wob, out, SEQL, DIMM, DIMM);
}

// Round 2
// 469.744 us; speedup vs baseline: 1.1756x; 1.1756x over previous
//
#include <hip/hip_runtime.h>

typedef __bf16 bf16_t;
typedef __bf16 bf16x8 __attribute__((ext_vector_type(8)));
typedef __bf16 bf16x4 __attribute__((ext_vector_type(4)));
typedef float f32x4 __attribute__((ext_vector_type(4)));

#define SEQL 2048
#define DIMM 4096
#define NH 32
#define NKV 8
#define HD 128

__device__ __forceinline__ void gl2lds16(const void* g, void* l) {
  __builtin_amdgcn_global_load_lds((__attribute__((address_space(1))) void*)g,
                                   (__attribute__((address_space(3))) void*)l,
                                   16, 0, 0);
}

// ---------------- fused fp32 -> bf16 convert of all 5 tensors ----------------
// dst contiguous: [x (8388608)][wq (16777216)][wk (4194304)][wv (4194304)][wo (16777216)]
__global__ __launch_bounds__(256) void cvt5_kernel(const float* __restrict__ s0,
                                                   const float* __restrict__ s1,
                                                   const float* __restrict__ s2,
                                                   const float* __restrict__ s3,
                                                   const float* __restrict__ s4,
                                                   bf16_t* __restrict__ dst) {
  long i4 = (long)blockIdx.x * 256 + threadIdx.x;
  long e = i4 * 4;
  const float* s;
  long o;
  if (e < 8388608L)       { s = s0; o = e; }
  else if (e < 25165824L) { s = s1; o = e - 8388608L; }
  else if (e < 29360128L) { s = s2; o = e - 25165824L; }
  else if (e < 33554432L) { s = s3; o = e - 29360128L; }
  else                    { s = s4; o = e - 33554432L; }
  float4 v = *(const float4*)(s + o);
  bf16x4 ov;
  ov[0] = (bf16_t)v.x; ov[1] = (bf16_t)v.y; ov[2] = (bf16_t)v.z; ov[3] = (bf16_t)v.w;
  *(bf16x4*)(dst + e) = ov;
}

// ---------------- NT GEMM: C[M,N] = A[M,K] * B[N,K]^T (bf16 in) --------------
// 128x128 tile, BK=64, XOR-swizzled LDS, XCD-aware block swizzle (M fixed = 2048
// -> 16 m-tiles hardcoded). 256 threads, 4 waves 2x2 of 64x64, 16x16x32 MFMA.
// CT = float or bf16_t output.
template <typename CT>
__global__ __launch_bounds__(256, 3) void gemm_bt_kernel(const bf16_t* __restrict__ A,
                                                         const bf16_t* __restrict__ B,
                                                         CT* __restrict__ C,
                                                         int N, int K, int npanel) {
  __shared__ bf16_t lA[128 * 64];
  __shared__ bf16_t lB[128 * 64];
  const int tid = threadIdx.x;
  // XCD swizzle: consecutive blocks round-robin XCDs; give each XCD an n-panel.
  const int lin = blockIdx.x;
  const int xcd = lin & 7, idx = lin >> 3;
  const int bm = (idx & 15) * 128;
  const int bn = ((idx >> 4) + xcd * npanel) * 128;
  const int lane = tid & 63, wave = tid >> 6;
  const int wm = (wave >> 1) * 64, wn = (wave & 1) * 64;
  const int lr = lane & 15, quad = lane >> 4;

  f32x4 acc[4][4];
#pragma unroll
  for (int mi = 0; mi < 4; ++mi)
#pragma unroll
    for (int ni = 0; ni < 4; ++ni)
      acc[mi][ni] = (f32x4){0.f, 0.f, 0.f, 0.f};

  // staging: slot s (0..1023) holds row s>>3, col-block (s&7)^((s>>3)&7) (XOR swizzle)
  long soff[4];
#pragma unroll
  for (int c = 0; c < 4; ++c) {
    const int s = tid + 256 * c;
    soff[c] = (long)(s >> 3) * K + (((s & 7) ^ ((s >> 3) & 7)) << 3);
  }
  const bf16_t* Abase = A + (long)bm * K;
  const bf16_t* Bbase = B + (long)bn * K;

  for (int k0 = 0; k0 < K; k0 += 64) {
    __syncthreads();
#pragma unroll
    for (int c = 0; c < 4; ++c) {
      gl2lds16(Abase + soff[c] + k0, lA + (tid + 256 * c) * 8);
      gl2lds16(Bbase + soff[c] + k0, lB + (tid + 256 * c) * 8);
    }
    __syncthreads();
#pragma unroll
    for (int ks = 0; ks < 2; ++ks) {
      bf16x8 af[4], bfr[4];
#pragma unroll
      for (int mi = 0; mi < 4; ++mi)
        af[mi] = *(const bf16x8*)&lA[(wm + mi * 16 + lr) * 64 + ((((ks << 2) | quad) ^ (lr & 7)) << 3)];
#pragma unroll
      for (int ni = 0; ni < 4; ++ni)
        bfr[ni] = *(const bf16x8*)&lB[(wn + ni * 16 + lr) * 64 + ((((ks << 2) | quad) ^ (lr & 7)) << 3)];
#pragma unroll
      for (int mi = 0; mi < 4; ++mi)
#pragma unroll
        for (int ni = 0; ni < 4; ++ni)
          acc[mi][ni] = __builtin_amdgcn_mfma_f32_16x16x32_bf16(af[mi], bfr[ni], acc[mi][ni], 0, 0, 0);
    }
  }

#pragma unroll
  for (int mi = 0; mi < 4; ++mi) {
    const int row = bm + wm + mi * 16 + quad * 4;
#pragma unroll
    for (int ni = 0; ni < 4; ++ni) {
      const int col = bn + wn + ni * 16 + lr;
      CT* cp = C + (long)row * N + col;
#pragma unroll
      for (int r = 0; r < 4; ++r) cp[(long)r * N] = (CT)acc[mi][ni][r];
    }
  }
}

// ---------------- fused per-head RMSNorm + RoPE, bf16 -> bf16, [s][h*128] -> [h][s][128]
__global__ __launch_bounds__(256) void rmsrope_kernel(const bf16_t* __restrict__ xf, // + col offset
                                                      int rstride,
                                                      const float* __restrict__ nw,
                                                      const float* __restrict__ rope,
                                                      const int* __restrict__ pos,
                                                      bf16_t* __restrict__ out,
                                                      int H) {
  const int wave = threadIdx.x >> 6, lane = threadIdx.x & 63;
  const int flat = blockIdx.x * 4 + wave;
  const int s = flat / H, h = flat - s * H;
  const bf16_t* xp = xf + (long)s * rstride + h * HD;
  float x1 = (float)xp[lane], x2 = (float)xp[lane + 64];
  float ss = x1 * x1 + x2 * x2;
#pragma unroll
  for (int off = 32; off > 0; off >>= 1) ss += __shfl_xor(ss, off, 64);
  const float sc = rsqrtf(ss * (1.0f / 128.0f) + 1e-6f);
  const float n1 = x1 * sc * nw[lane];
  const float n2 = x2 * sc * nw[lane + 64];
  const int p = pos[s];
  const float c = rope[p * 128 + lane * 2];
  const float sn = rope[p * 128 + lane * 2 + 1];
  bf16_t* op = out + ((long)h * SEQL + s) * HD;
  op[lane] = (bf16_t)(n1 * c - n2 * sn);
  op[lane + 64] = (bf16_t)(n2 * c + n1 * sn);
}

// ---------------- V transpose: bf16 [s][(col off)+hk*128+d] -> bf16 [hk][d][s] ----
__global__ __launch_bounds__(256) void vtrans_kernel(const bf16_t* __restrict__ vf, // + col offset
                                                     int rstride,
                                                     bf16_t* __restrict__ vb) {
  __shared__ bf16_t lt[128 * 129];
  const int hk = blockIdx.x >> 4;
  const int s0 = (blockIdx.x & 15) * 128;
  const int t = threadIdx.x;
  for (int i = t; i < 128 * 128; i += 256) {
    const int sl = i >> 7, d = i & 127;
    lt[sl * 129 + d] = vf[(long)(s0 + sl) * rstride + hk * HD + d];
  }
  __syncthreads();
#pragma unroll
  for (int cc = 0; cc < 8; ++cc) {
    const int cidx = t + 256 * cc;
    const int d = cidx >> 4, sc = (cidx & 15) * 8;
    bf16x8 v;
#pragma unroll
    for (int j = 0; j < 8; ++j) v[j] = lt[(sc + j) * 129 + d];
    *(bf16x8*)(vb + ((long)hk * HD + d) * SEQL + s0 + sc) = v;
  }
}

// ---------------- flash attention, block-diag causal (4 segments of 512) ----
// Q [32][2048][128], K [8][2048][128], V [8][128][2048] (bf16), O bf16 [2048][4096]
#define CK 64
#define PSTR 72
__global__ __launch_bounds__(256) void attn_kernel(const bf16_t* __restrict__ Q,
                                                   const bf16_t* __restrict__ Kt,
                                                   const bf16_t* __restrict__ Vt,
                                                   bf16_t* __restrict__ O) {
  __shared__ bf16_t lK[CK * 128];    // [kk][d]
  __shared__ bf16_t lV[128 * CK];    // [d][kk]
  __shared__ bf16_t lP[128 * PSTR];  // [m][kk]
  const int qb = 3 - blockIdx.x;     // heaviest q-blocks dispatched first
  const int g = blockIdx.y, h = blockIdx.z;
  const int hk = h >> 2;
  const int tid = threadIdx.x, lane = tid & 63, wave = tid >> 6;
  const int lr = lane & 15, quad = lane >> 4;
  const int s_base = g * 512 + qb * 128;

  bf16x8 qf[2][4];
  const bf16_t* Qp = Q + ((long)h * SEQL + s_base + wave * 32 + lr) * HD + quad * 8;
#pragma unroll
  for (int mi = 0; mi < 2; ++mi)
#pragma unroll
    for (int ks = 0; ks < 4; ++ks)
      qf[mi][ks] = *(const bf16x8*)(Qp + mi * 16 * HD + ks * 32);

  f32x4 oacc[2][8];
#pragma unroll
  for (int mi = 0; mi < 2; ++mi)
#pragma unroll
    for (int di = 0; di < 8; ++di) oacc[mi][di] = (f32x4){0.f, 0.f, 0.f, 0.f};
  float mst[2][4], lst[2][4];
#pragma unroll
  for (int mi = 0; mi < 2; ++mi)
#pragma unroll
    for (int r = 0; r < 4; ++r) { mst[mi][r] = -3.0e38f; lst[mi][r] = 0.f; }

  const float c1 = 0.08838834764831845f * 1.4426950408889634f;  // scale * log2(e)

  const int nchunk = 2 * qb + 2;
  for (int c = 0; c < nchunk; ++c) {
    __syncthreads();
    {
      const bf16_t* Kg = Kt + ((long)hk * SEQL + g * 512 + c * CK) * HD;
      const bf16_t* Vg = Vt + (long)hk * HD * SEQL + g * 512 + c * CK;
#pragma unroll
      for (int cc = 0; cc < 4; ++cc) {
        const int i = tid + 256 * cc;
        gl2lds16(Kg + (long)(i >> 4) * HD + (i & 15) * 8, lK + i * 8);
        gl2lds16(Vg + (long)(i >> 3) * SEQL + (i & 7) * 8, lV + i * 8);
      }
    }
    __syncthreads();

    f32x4 sv[2][4];
#pragma unroll
    for (int mi = 0; mi < 2; ++mi)
#pragma unroll
      for (int ni = 0; ni < 4; ++ni) sv[mi][ni] = (f32x4){0.f, 0.f, 0.f, 0.f};
#pragma unroll
    for (int ks = 0; ks < 4; ++ks) {
#pragma unroll
      for (int ni = 0; ni < 4; ++ni) {
        const bf16x8 kf = *(const bf16x8*)&lK[(ni * 16 + lr) * 128 + ks * 32 + quad * 8];
        sv[0][ni] = __builtin_amdgcn_mfma_f32_16x16x32_bf16(qf[0][ks], kf, sv[0][ni], 0, 0, 0);
        sv[1][ni] = __builtin_amdgcn_mfma_f32_16x16x32_bf16(qf[1][ks], kf, sv[1][ni], 0, 0, 0);
      }
    }

    // scale to log2 domain + causal mask
#pragma unroll
    for (int mi = 0; mi < 2; ++mi)
#pragma unroll
      for (int ni = 0; ni < 4; ++ni)
#pragma unroll
        for (int r = 0; r < 4; ++r) {
          const int colseg = c * CK + ni * 16 + lr;
          const int rowseg = qb * 128 + wave * 32 + mi * 16 + quad * 4 + r;
          const float v = sv[mi][ni][r] * c1;
          sv[mi][ni][r] = (colseg > rowseg) ? -3.0e38f : v;
        }

    // online softmax (rows live in 16-lane groups)
#pragma unroll
    for (int mi = 0; mi < 2; ++mi)
#pragma unroll
      for (int r = 0; r < 4; ++r) {
        float rm = sv[mi][0][r];
#pragma unroll
        for (int ni = 1; ni < 4; ++ni) rm = fmaxf(rm, sv[mi][ni][r]);
        rm = fmaxf(rm, __shfl_xor(rm, 1, 64));
        rm = fmaxf(rm, __shfl_xor(rm, 2, 64));
        rm = fmaxf(rm, __shfl_xor(rm, 4, 64));
        rm = fmaxf(rm, __shfl_xor(rm, 8, 64));
        const float mnew = fmaxf(mst[mi][r], rm);
        const float alpha = exp2f(mst[mi][r] - mnew);
        mst[mi][r] = mnew;
        float ps = 0.f;
#pragma unroll
        for (int ni = 0; ni < 4; ++ni) {
          const float p = exp2f(sv[mi][ni][r] - mnew);
          sv[mi][ni][r] = p;
          ps += p;
        }
        ps += __shfl_xor(ps, 1, 64);
        ps += __shfl_xor(ps, 2, 64);
        ps += __shfl_xor(ps, 4, 64);
        ps += __shfl_xor(ps, 8, 64);
        lst[mi][r] = lst[mi][r] * alpha + ps;
#pragma unroll
        for (int di = 0; di < 8; ++di) oacc[mi][di][r] *= alpha;
      }

    // P: C-layout -> LDS [m][kk] (read back in A-layout)
#pragma unroll
    for (int mi = 0; mi < 2; ++mi)
#pragma unroll
      for (int ni = 0; ni < 4; ++ni)
#pragma unroll
        for (int r = 0; r < 4; ++r)
          lP[(wave * 32 + mi * 16 + quad * 4 + r) * PSTR + ni * 16 + lr] = (bf16_t)sv[mi][ni][r];
    __syncthreads();

    // O += P @ V
#pragma unroll
    for (int ks = 0; ks < 2; ++ks) {
      const bf16x8 pf0 = *(const bf16x8*)&lP[(wave * 32 + lr) * PSTR + ks * 32 + quad * 8];
      const bf16x8 pf1 = *(const bf16x8*)&lP[(wave * 32 + 16 + lr) * PSTR + ks * 32 + quad * 8];
#pragma unroll
      for (int di = 0; di < 8; ++di) {
        const bf16x8 vfr = *(const bf16x8*)&lV[(di * 16 + lr) * CK + ks * 32 + quad * 8];
        oacc[0][di] = __builtin_amdgcn_mfma_f32_16x16x32_bf16(pf0, vfr, oacc[0][di], 0, 0, 0);
        oacc[1][di] = __builtin_amdgcn_mfma_f32_16x16x32_bf16(pf1, vfr, oacc[1][di], 0, 0, 0);
      }
    }
  }

  // epilogue: O[s][h*128+d] bf16
#pragma unroll
  for (int mi = 0; mi < 2; ++mi)
#pragma unroll
    for (int r = 0; r < 4; ++r) {
      const float inv = 1.0f / lst[mi][r];
      const int row = s_base + wave * 32 + mi * 16 + quad * 4 + r;
      bf16_t* opp = O + (long)row * DIMM + h * HD + lr;
#pragma unroll
      for (int di = 0; di < 8; ++di) opp[di * 16] = (bf16_t)(oacc[mi][di][r] * inv);
    }
}

// -----------------------------------------------------------------------------
extern "C" void kernel_launch(void* const* d_in, const int* in_sizes, int n_in,
                              void* d_out, int out_size, void* d_ws, size_t ws_size,
                              hipStream_t stream) {
  (void)in_sizes; (void)n_in; (void)out_size; (void)ws_size;
  const float* x    = (const float*)d_in[0];
  const float* wq   = (const float*)d_in[1];
  const float* wk   = (const float*)d_in[2];
  const float* wv   = (const float*)d_in[3];
  const float* wo   = (const float*)d_in[4];
  const float* qnw  = (const float*)d_in[5];
  const float* knw  = (const float*)d_in[6];
  const float* rope = (const float*)d_in[7];
  const int*   pos  = (const int*)d_in[8];
  float* out = (float*)d_out;

  char* ws = (char*)d_ws;
  size_t off = 0;
  auto alloc = [&](size_t b) { char* p = ws + off; off += (b + 255) & ~(size_t)255; return p; };
  // first five allocations must stay contiguous (cvt5 writes them as one region)
  bf16_t* xb    = (bf16_t*)alloc((size_t)SEQL * DIMM * 2);          // 16 MiB
  bf16_t* wqkvb = (bf16_t*)alloc((size_t)DIMM * DIMM * 2);          // wq part, 32 MiB
  alloc((size_t)NKV * HD * DIMM * 2);                               // wk part (contiguous)
  alloc((size_t)NKV * HD * DIMM * 2);                               // wv part (contiguous)
  bf16_t* wob   = (bf16_t*)alloc((size_t)DIMM * DIMM * 2);          // 32 MiB
  bf16_t* qkvb  = (bf16_t*)alloc((size_t)SEQL * 6144 * 2);          // 24 MiB
  // aliases into regions dead by the time they're written:
  bf16_t* Qb    = (bf16_t*)wqkvb;                // [32][2048][128], wqkv dead after QKV GEMM
  bf16_t* Kb    = Qb + (size_t)NH * SEQL * HD;   // [8][2048][128]
  bf16_t* Vb    = Kb + (size_t)NKV * SEQL * HD;  // [8][128][2048]
  bf16_t* attnb = xb;                            // [2048][4096], xb dead after QKV GEMM

  // 1) convert all inputs to bf16
  cvt5_kernel<<<dim3(49152), 256, 0, stream>>>(x, wq, wk, wv, wo, xb);
  // 2) fused QKV projection: [2048][6144] = xb @ [wq;wk;wv]^T  (bf16 out)
  gemm_bt_kernel<bf16_t><<<dim3(768), 256, 0, stream>>>(xb, wqkvb, qkvb, 6144, DIMM, 6);
  // 3) RMSNorm + RoPE for Q and K (head-major bf16 out)
  rmsrope_kernel<<<dim3(SEQL * NH / 4), 256, 0, stream>>>(qkvb, 6144, qnw, rope, pos, Qb, NH);
  rmsrope_kernel<<<dim3(SEQL * NKV / 4), 256, 0, stream>>>(qkvb + 4096, 6144, knw, rope, pos, Kb, NKV);
  // 4) V transpose to [hk][d][s] bf16
  vtrans_kernel<<<dim3(NKV * 16), 256, 0, stream>>>(qkvb + 5120, 6144, Vb);
  // 5) attention
  attn_kernel<<<dim3(4, 4, NH), 256, 0, stream>>>(Qb, Kb, Vb, attnb);
  // 6) output projection -> fp32 d_out
  gemm_bt_kernel<float><<<dim3(512), 256, 0, stream>>>(attnb, wob, out, DIMM, DIMM, 4);
}

// Round 3
// 461.401 us; speedup vs baseline: 1.1969x; 1.0181x over previous
//
#include <hip/hip_runtime.h>

typedef __bf16 bf16_t;
typedef __bf16 bf16x8 __attribute__((ext_vector_type(8)));
typedef __bf16 bf16x4 __attribute__((ext_vector_type(4)));
typedef float f32x4 __attribute__((ext_vector_type(4)));

#define SEQL 2048
#define DIMM 4096
#define NH 32
#define NKV 8
#define HD 128

__device__ __forceinline__ void gl2lds16(const void* g, void* l) {
  __builtin_amdgcn_global_load_lds((__attribute__((address_space(1))) void*)g,
                                   (__attribute__((address_space(3))) void*)l,
                                   16, 0, 0);
}

// ---------------- fused fp32 -> bf16 convert of all 5 tensors ----------------
// dst contiguous: [x][wq][wk][wv][wo]; each block handles 4096 floats (region
// boundaries are multiples of 4096 so the branch is block-uniform).
__global__ __launch_bounds__(256) void cvt5_kernel(const float* __restrict__ s0,
                                                   const float* __restrict__ s1,
                                                   const float* __restrict__ s2,
                                                   const float* __restrict__ s3,
                                                   const float* __restrict__ s4,
                                                   bf16_t* __restrict__ dst) {
  const long base = (long)blockIdx.x * 4096;
  const float* s;
  long o;
  if (base < 8388608L)       { s = s0; o = base; }
  else if (base < 25165824L) { s = s1; o = base - 8388608L; }
  else if (base < 29360128L) { s = s2; o = base - 25165824L; }
  else if (base < 33554432L) { s = s3; o = base - 29360128L; }
  else                       { s = s4; o = base - 33554432L; }
  const long t4 = threadIdx.x * 4;
#pragma unroll
  for (int j = 0; j < 4; ++j) {
    const long e = t4 + j * 1024;
    float4 v = *(const float4*)(s + o + e);
    bf16x4 ov;
    ov[0] = (bf16_t)v.x; ov[1] = (bf16_t)v.y; ov[2] = (bf16_t)v.z; ov[3] = (bf16_t)v.w;
    *(bf16x4*)(dst + base + e) = ov;
  }
}

// ---------------- NT GEMM: C[M,N] = A[M,K] * B[N,K]^T (bf16 in) --------------
// 128x128 tile, BK=64, XOR-swizzled LDS, XCD-aware block swizzle (M fixed = 2048
// -> 16 m-tiles hardcoded). 256 threads, 4 waves 2x2 of 64x64, 16x16x32 MFMA.
template <typename CT>
__global__ __launch_bounds__(256, 3) void gemm_bt_kernel(const bf16_t* __restrict__ A,
                                                         const bf16_t* __restrict__ B,
                                                         CT* __restrict__ C,
                                                         int N, int K, int npanel) {
  __shared__ bf16_t lA[128 * 64];
  __shared__ bf16_t lB[128 * 64];
  const int tid = threadIdx.x;
  const int lin = blockIdx.x;
  const int xcd = lin & 7, idx = lin >> 3;
  const int bm = (idx & 15) * 128;
  const int bn = ((idx >> 4) + xcd * npanel) * 128;
  const int lane = tid & 63, wave = tid >> 6;
  const int wm = (wave >> 1) * 64, wn = (wave & 1) * 64;
  const int lr = lane & 15, quad = lane >> 4;

  f32x4 acc[4][4];
#pragma unroll
  for (int mi = 0; mi < 4; ++mi)
#pragma unroll
    for (int ni = 0; ni < 4; ++ni)
      acc[mi][ni] = (f32x4){0.f, 0.f, 0.f, 0.f};

  long soff[4];
#pragma unroll
  for (int c = 0; c < 4; ++c) {
    const int s = tid + 256 * c;
    soff[c] = (long)(s >> 3) * K + (((s & 7) ^ ((s >> 3) & 7)) << 3);
  }
  const bf16_t* Abase = A + (long)bm * K;
  const bf16_t* Bbase = B + (long)bn * K;

  for (int k0 = 0; k0 < K; k0 += 64) {
    __syncthreads();
#pragma unroll
    for (int c = 0; c < 4; ++c) {
      gl2lds16(Abase + soff[c] + k0, lA + (tid + 256 * c) * 8);
      gl2lds16(Bbase + soff[c] + k0, lB + (tid + 256 * c) * 8);
    }
    __syncthreads();
#pragma unroll
    for (int ks = 0; ks < 2; ++ks) {
      bf16x8 af[4], bfr[4];
#pragma unroll
      for (int mi = 0; mi < 4; ++mi)
        af[mi] = *(const bf16x8*)&lA[(wm + mi * 16 + lr) * 64 + ((((ks << 2) | quad) ^ (lr & 7)) << 3)];
#pragma unroll
      for (int ni = 0; ni < 4; ++ni)
        bfr[ni] = *(const bf16x8*)&lB[(wn + ni * 16 + lr) * 64 + ((((ks << 2) | quad) ^ (lr & 7)) << 3)];
#pragma unroll
      for (int mi = 0; mi < 4; ++mi)
#pragma unroll
        for (int ni = 0; ni < 4; ++ni)
          acc[mi][ni] = __builtin_amdgcn_mfma_f32_16x16x32_bf16(af[mi], bfr[ni], acc[mi][ni], 0, 0, 0);
    }
  }

#pragma unroll
  for (int mi = 0; mi < 4; ++mi) {
    const int row = bm + wm + mi * 16 + quad * 4;
#pragma unroll
    for (int ni = 0; ni < 4; ++ni) {
      const int col = bn + wn + ni * 16 + lr;
      CT* cp = C + (long)row * N + col;
#pragma unroll
      for (int r = 0; r < 4; ++r) cp[(long)r * N] = (CT)acc[mi][ni][r];
    }
  }
}

// ---------------- fused per-head RMSNorm + RoPE, bf16 -> bf16 ----------------
// [s][h*128] -> [h][s][128]; oscale folds softmax scale*log2(e) into Q.
__global__ __launch_bounds__(256) void rmsrope_kernel(const bf16_t* __restrict__ xf,
                                                      int rstride,
                                                      const float* __restrict__ nw,
                                                      const float* __restrict__ rope,
                                                      const int* __restrict__ pos,
                                                      bf16_t* __restrict__ out,
                                                      int H, float oscale) {
  const int wave = threadIdx.x >> 6, lane = threadIdx.x & 63;
  const int flat = blockIdx.x * 4 + wave;
  const int s = flat / H, h = flat - s * H;
  const bf16_t* xp = xf + (long)s * rstride + h * HD;
  float x1 = (float)xp[lane], x2 = (float)xp[lane + 64];
  float ss = x1 * x1 + x2 * x2;
#pragma unroll
  for (int off = 32; off > 0; off >>= 1) ss += __shfl_xor(ss, off, 64);
  const float sc = rsqrtf(ss * (1.0f / 128.0f) + 1e-6f) * oscale;
  const float n1 = x1 * sc * nw[lane];
  const float n2 = x2 * sc * nw[lane + 64];
  const int p = pos[s];
  const float c = rope[p * 128 + lane * 2];
  const float sn = rope[p * 128 + lane * 2 + 1];
  bf16_t* op = out + ((long)h * SEQL + s) * HD;
  op[lane] = (bf16_t)(n1 * c - n2 * sn);
  op[lane + 64] = (bf16_t)(n2 * c + n1 * sn);
}

// ---------------- V transpose: bf16 [s][col+hk*128+d] -> bf16 [hk][d][s] -----
__global__ __launch_bounds__(256) void vtrans_kernel(const bf16_t* __restrict__ vf,
                                                     int rstride,
                                                     bf16_t* __restrict__ vb) {
  __shared__ bf16_t lt[128 * 129];
  const int hk = blockIdx.x >> 4;
  const int s0 = (blockIdx.x & 15) * 128;
  const int t = threadIdx.x;
  for (int i = t; i < 128 * 128; i += 256) {
    const int sl = i >> 7, d = i & 127;
    lt[sl * 129 + d] = vf[(long)(s0 + sl) * rstride + hk * HD + d];
  }
  __syncthreads();
#pragma unroll
  for (int cc = 0; cc < 8; ++cc) {
    const int cidx = t + 256 * cc;
    const int d = cidx >> 4, sc = (cidx & 15) * 8;
    bf16x8 v;
#pragma unroll
    for (int j = 0; j < 8; ++j) v[j] = lt[(sc + j) * 129 + d];
    *(bf16x8*)(vb + ((long)hk * HD + d) * SEQL + s0 + sc) = v;
  }
}

// ---------------- flash attention, block-diag causal, FIXED-RANGE softmax ----
// RMSNorm bounds |score| <= 0.0884*128 = 11.32 -> exp2(s) can't overflow fp32;
// no running max / alpha rescale needed. scale*log2e pre-folded into Q.
// Row-sum l comes from PV MFMA via 16 ones-rows appended to V in LDS (di=8).
// Q [32][2048][128], K [8][2048][128], V [8][128][2048] (bf16), O bf16 [2048][4096]
#define CK 64
#define PSTR 72
__global__ __launch_bounds__(256) void attn_kernel(const bf16_t* __restrict__ Q,
                                                   const bf16_t* __restrict__ Kt,
                                                   const bf16_t* __restrict__ Vt,
                                                   bf16_t* __restrict__ O) {
  __shared__ bf16_t lK[CK * 128];    // [kk][d]
  __shared__ bf16_t lV[144 * CK];    // [d][kk]; rows 128..143 = ones (l trick)
  __shared__ bf16_t lP[128 * PSTR];  // [m][kk]
  // complementary qb pairing: blocks i and i+256 share a CU -> qb sums to 3.
  const int lin = blockIdx.x;
  const int qb = (lin < 256) ? (3 - (lin & 1)) : (lin & 1);
  const int gh = (lin >> 1) & 127;
  const int h = gh & 31, g = gh >> 5;
  const int hk = h >> 2;
  const int tid = threadIdx.x, lane = tid & 63, wave = tid >> 6;
  const int lr = lane & 15, quad = lane >> 4;
  const int s_base = g * 512 + qb * 128;

  // ones rows for the l trick (written once; covered by loop-top barrier)
  if (tid < 128) {
    bf16x8 one8;
#pragma unroll
    for (int j = 0; j < 8; ++j) one8[j] = (bf16_t)1.0f;
    *(bf16x8*)&lV[128 * CK + tid * 8] = one8;
  }

  bf16x8 qf[2][4];
  const bf16_t* Qp = Q + ((long)h * SEQL + s_base + wave * 32 + lr) * HD + quad * 8;
#pragma unroll
  for (int mi = 0; mi < 2; ++mi)
#pragma unroll
    for (int ks = 0; ks < 4; ++ks)
      qf[mi][ks] = *(const bf16x8*)(Qp + mi * 16 * HD + ks * 32);

  f32x4 oacc[2][9];
#pragma unroll
  for (int mi = 0; mi < 2; ++mi)
#pragma unroll
    for (int di = 0; di < 9; ++di) oacc[mi][di] = (f32x4){0.f, 0.f, 0.f, 0.f};

  const int nchunk = 2 * qb + 2;
  for (int c = 0; c < nchunk; ++c) {
    __syncthreads();
    {
      const bf16_t* Kg = Kt + ((long)hk * SEQL + g * 512 + c * CK) * HD;
      const bf16_t* Vg = Vt + (long)hk * HD * SEQL + g * 512 + c * CK;
#pragma unroll
      for (int cc = 0; cc < 4; ++cc) {
        const int i = tid + 256 * cc;
        gl2lds16(Kg + (long)(i >> 4) * HD + (i & 15) * 8, lK + i * 8);
        gl2lds16(Vg + (long)(i >> 3) * SEQL + (i & 7) * 8, lV + i * 8);
      }
    }
    __syncthreads();

    f32x4 sv[2][4];
#pragma unroll
    for (int mi = 0; mi < 2; ++mi)
#pragma unroll
      for (int ni = 0; ni < 4; ++ni) sv[mi][ni] = (f32x4){0.f, 0.f, 0.f, 0.f};
#pragma unroll
    for (int ks = 0; ks < 4; ++ks) {
#pragma unroll
      for (int ni = 0; ni < 4; ++ni) {
        const bf16x8 kf = *(const bf16x8*)&lK[(ni * 16 + lr) * 128 + ks * 32 + quad * 8];
        sv[0][ni] = __builtin_amdgcn_mfma_f32_16x16x32_bf16(qf[0][ks], kf, sv[0][ni], 0, 0, 0);
        sv[1][ni] = __builtin_amdgcn_mfma_f32_16x16x32_bf16(qf[1][ks], kf, sv[1][ni], 0, 0, 0);
      }
    }

    // p = exp2(s) (scale folded into Q), mask, straight to LDS in A-layout
#pragma unroll
    for (int mi = 0; mi < 2; ++mi)
#pragma unroll
      for (int ni = 0; ni < 4; ++ni)
#pragma unroll
        for (int r = 0; r < 4; ++r) {
          const int colseg = c * CK + ni * 16 + lr;
          const int rowseg = qb * 128 + wave * 32 + mi * 16 + quad * 4 + r;
          float p = exp2f(sv[mi][ni][r]);
          p = (colseg > rowseg) ? 0.f : p;
          lP[(wave * 32 + mi * 16 + quad * 4 + r) * PSTR + ni * 16 + lr] = (bf16_t)p;
        }
    __syncthreads();

    // O += P @ [V ; ones] (di=8 accumulates the row-sum l)
#pragma unroll
    for (int ks = 0; ks < 2; ++ks) {
      const bf16x8 pf0 = *(const bf16x8*)&lP[(wave * 32 + lr) * PSTR + ks * 32 + quad * 8];
      const bf16x8 pf1 = *(const bf16x8*)&lP[(wave * 32 + 16 + lr) * PSTR + ks * 32 + quad * 8];
#pragma unroll
      for (int di = 0; di < 9; ++di) {
        const bf16x8 vfr = *(const bf16x8*)&lV[(di * 16 + lr) * CK + ks * 32 + quad * 8];
        oacc[0][di] = __builtin_amdgcn_mfma_f32_16x16x32_bf16(pf0, vfr, oacc[0][di], 0, 0, 0);
        oacc[1][di] = __builtin_amdgcn_mfma_f32_16x16x32_bf16(pf1, vfr, oacc[1][di], 0, 0, 0);
      }
    }
  }

  // epilogue: O[s][h*128+d] = oacc/l
#pragma unroll
  for (int mi = 0; mi < 2; ++mi)
#pragma unroll
    for (int r = 0; r < 4; ++r) {
      const float inv = 1.0f / oacc[mi][8][r];
      const int row = s_base + wave * 32 + mi * 16 + quad * 4 + r;
      bf16_t* opp = O + (long)row * DIMM + h * HD + lr;
#pragma unroll
      for (int di = 0; di < 8; ++di) opp[di * 16] = (bf16_t)(oacc[mi][di][r] * inv);
    }
}

// -----------------------------------------------------------------------------
extern "C" void kernel_launch(void* const* d_in, const int* in_sizes, int n_in,
                              void* d_out, int out_size, void* d_ws, size_t ws_size,
                              hipStream_t stream) {
  (void)in_sizes; (void)n_in; (void)out_size; (void)ws_size;
  const float* x    = (const float*)d_in[0];
  const float* wq   = (const float*)d_in[1];
  const float* wk   = (const float*)d_in[2];
  const float* wv   = (const float*)d_in[3];
  const float* wo   = (const float*)d_in[4];
  const float* qnw  = (const float*)d_in[5];
  const float* knw  = (const float*)d_in[6];
  const float* rope = (const float*)d_in[7];
  const int*   pos  = (const int*)d_in[8];
  float* out = (float*)d_out;

  char* ws = (char*)d_ws;
  size_t off = 0;
  auto alloc = [&](size_t b) { char* p = ws + off; off += (b + 255) & ~(size_t)255; return p; };
  // first five allocations must stay contiguous (cvt5 writes them as one region)
  bf16_t* xb    = (bf16_t*)alloc((size_t)SEQL * DIMM * 2);          // 16 MiB
  bf16_t* wqkvb = (bf16_t*)alloc((size_t)DIMM * DIMM * 2);          // wq part, 32 MiB
  alloc((size_t)NKV * HD * DIMM * 2);                               // wk part (contiguous)
  alloc((size_t)NKV * HD * DIMM * 2);                               // wv part (contiguous)
  bf16_t* wob   = (bf16_t*)alloc((size_t)DIMM * DIMM * 2);          // 32 MiB
  bf16_t* qkvb  = (bf16_t*)alloc((size_t)SEQL * 6144 * 2);          // 24 MiB
  // aliases into regions dead by the time they're written:
  bf16_t* Qb    = (bf16_t*)wqkvb;                // [32][2048][128], wqkv dead after QKV GEMM
  bf16_t* Kb    = Qb + (size_t)NH * SEQL * HD;   // [8][2048][128]
  bf16_t* Vb    = Kb + (size_t)NKV * SEQL * HD;  // [8][128][2048]
  bf16_t* attnb = xb;                            // [2048][4096], xb dead after QKV GEMM

  const float c1 = 0.08838834764831845f * 1.4426950408889634f;  // scale * log2(e)

  // 1) convert all inputs to bf16
  cvt5_kernel<<<dim3(12288), 256, 0, stream>>>(x, wq, wk, wv, wo, xb);
  // 2) fused QKV projection: [2048][6144] = xb @ [wq;wk;wv]^T  (bf16 out)
  gemm_bt_kernel<bf16_t><<<dim3(768), 256, 0, stream>>>(xb, wqkvb, qkvb, 6144, DIMM, 6);
  // 3) RMSNorm + RoPE for Q (scale folded) and K (head-major bf16 out)
  rmsrope_kernel<<<dim3(SEQL * NH / 4), 256, 0, stream>>>(qkvb, 6144, qnw, rope, pos, Qb, NH, c1);
  rmsrope_kernel<<<dim3(SEQL * NKV / 4), 256, 0, stream>>>(qkvb + 4096, 6144, knw, rope, pos, Kb, NKV, 1.0f);
  // 4) V transpose to [hk][d][s] bf16
  vtrans_kernel<<<dim3(NKV * 16), 256, 0, stream>>>(qkvb + 5120, 6144, Vb);
  // 5) attention (512 blocks, complementary-qb pairing)
  attn_kernel<<<dim3(512), 256, 0, stream>>>(Qb, Kb, Vb, attnb);
  // 6) output projection -> fp32 d_out
  gemm_bt_kernel<float><<<dim3(512), 256, 0, stream>>>(attnb, wob, out, DIMM, DIMM, 4);
}

// Round 4
// 446.341 us; speedup vs baseline: 1.2372x; 1.0337x over previous
//
#include <hip/hip_runtime.h>

typedef __bf16 bf16_t;
typedef __bf16 bf16x8 __attribute__((ext_vector_type(8)));
typedef __bf16 bf16x4 __attribute__((ext_vector_type(4)));
typedef float f32x4 __attribute__((ext_vector_type(4)));

#define SEQL 2048
#define DIMM 4096
#define NH 32
#define NKV 8
#define HD 128

__device__ __forceinline__ void gl2lds16(const void* g, void* l) {
  __builtin_amdgcn_global_load_lds((__attribute__((address_space(1))) void*)g,
                                   (__attribute__((address_space(3))) void*)l,
                                   16, 0, 0);
}

// ---------------- fused fp32 -> bf16 convert of all 5 tensors ----------------
// dst contiguous: [x][wq][wk][wv][wo]; each block handles 4096 floats (region
// boundaries are multiples of 4096 so the branch is block-uniform).
__global__ __launch_bounds__(256) void cvt5_kernel(const float* __restrict__ s0,
                                                   const float* __restrict__ s1,
                                                   const float* __restrict__ s2,
                                                   const float* __restrict__ s3,
                                                   const float* __restrict__ s4,
                                                   bf16_t* __restrict__ dst) {
  const long base = (long)blockIdx.x * 4096;
  const float* s;
  long o;
  if (base < 8388608L)       { s = s0; o = base; }
  else if (base < 25165824L) { s = s1; o = base - 8388608L; }
  else if (base < 29360128L) { s = s2; o = base - 25165824L; }
  else if (base < 33554432L) { s = s3; o = base - 29360128L; }
  else                       { s = s4; o = base - 33554432L; }
  const long t4 = threadIdx.x * 4;
#pragma unroll
  for (int j = 0; j < 4; ++j) {
    const long e = t4 + j * 1024;
    float4 v = *(const float4*)(s + o + e);
    bf16x4 ov;
    ov[0] = (bf16_t)v.x; ov[1] = (bf16_t)v.y; ov[2] = (bf16_t)v.z; ov[3] = (bf16_t)v.w;
    *(bf16x4*)(dst + base + e) = ov;
  }
}

// ---------------- QKV GEMM with fused RMSNorm+RoPE+V-transpose epilogue ------
// C = x[2048,4096] @ [wq;wk;wv]^T ; each 128-col n-tile is exactly one head.
// Epilogue: C-tile -> LDS (stride 136) -> per-row RMSNorm+RoPE (Q/K) or
// transposed bf16 write (V). Q gets scale*log2(e) folded in for the attn exp2.
#define TS 136
#define QSCALE (0.08838834764831845f * 1.4426950408889634f)
__global__ __launch_bounds__(256, 3) void gemm_qkv_kernel(const bf16_t* __restrict__ A,
                                                          const bf16_t* __restrict__ B,
                                                          const float* __restrict__ qnw,
                                                          const float* __restrict__ knw,
                                                          const float* __restrict__ rope,
                                                          const int* __restrict__ pos,
                                                          bf16_t* __restrict__ Qb,
                                                          bf16_t* __restrict__ Kb,
                                                          bf16_t* __restrict__ Vb) {
  __shared__ __align__(16) bf16_t smem[128 * TS];  // 34816 B; carved: lA | lB
  bf16_t* lA = smem;
  bf16_t* lB = smem + 8192;
  const int K = DIMM, npanel = 6;
  const int tid = threadIdx.x;
  const int lin = blockIdx.x;
  const int xcd = lin & 7, idx = lin >> 3;
  const int bm = (idx & 15) * 128;
  const int bn = ((idx >> 4) + xcd * npanel) * 128;
  const int lane = tid & 63, wave = tid >> 6;
  const int wm = (wave >> 1) * 64, wn = (wave & 1) * 64;
  const int lr = lane & 15, quad = lane >> 4;

  f32x4 acc[4][4];
#pragma unroll
  for (int mi = 0; mi < 4; ++mi)
#pragma unroll
    for (int ni = 0; ni < 4; ++ni)
      acc[mi][ni] = (f32x4){0.f, 0.f, 0.f, 0.f};

  long soff[4];
#pragma unroll
  for (int c = 0; c < 4; ++c) {
    const int s = tid + 256 * c;
    soff[c] = (long)(s >> 3) * K + (((s & 7) ^ ((s >> 3) & 7)) << 3);
  }
  const bf16_t* Abase = A + (long)bm * K;
  const bf16_t* Bbase = B + (long)bn * K;

  for (int k0 = 0; k0 < K; k0 += 64) {
    __syncthreads();
#pragma unroll
    for (int c = 0; c < 4; ++c) {
      gl2lds16(Abase + soff[c] + k0, lA + (tid + 256 * c) * 8);
      gl2lds16(Bbase + soff[c] + k0, lB + (tid + 256 * c) * 8);
    }
    __syncthreads();
#pragma unroll
    for (int ks = 0; ks < 2; ++ks) {
      bf16x8 af[4], bfr[4];
#pragma unroll
      for (int mi = 0; mi < 4; ++mi)
        af[mi] = *(const bf16x8*)&lA[(wm + mi * 16 + lr) * 64 + ((((ks << 2) | quad) ^ (lr & 7)) << 3)];
#pragma unroll
      for (int ni = 0; ni < 4; ++ni)
        bfr[ni] = *(const bf16x8*)&lB[(wn + ni * 16 + lr) * 64 + ((((ks << 2) | quad) ^ (lr & 7)) << 3)];
#pragma unroll
      for (int mi = 0; mi < 4; ++mi)
#pragma unroll
        for (int ni = 0; ni < 4; ++ni)
          acc[mi][ni] = __builtin_amdgcn_mfma_f32_16x16x32_bf16(af[mi], bfr[ni], acc[mi][ni], 0, 0, 0);
    }
  }

  // ---- epilogue: C-tile -> LDS (bf16, stride TS) ----
  __syncthreads();  // all waves done reading lA/lB
  bf16_t* tile = smem;
#pragma unroll
  for (int mi = 0; mi < 4; ++mi)
#pragma unroll
    for (int ni = 0; ni < 4; ++ni)
#pragma unroll
      for (int r = 0; r < 4; ++r)
        tile[(wm + mi * 16 + quad * 4 + r) * TS + wn + ni * 16 + lr] = (bf16_t)acc[mi][ni][r];
  __syncthreads();

  if (bn < 5120) {  // ---- Q or K head: RMSNorm + RoPE, write [h][s][128] ----
    const bool isQ = bn < 4096;
    const float* nwp = isQ ? qnw : knw;
    const float osc = isQ ? QSCALE : 1.0f;
    bf16_t* outp = isQ ? (Qb + (long)(bn >> 7) * SEQL * HD)
                       : (Kb + (long)((bn - 4096) >> 7) * SEQL * HD);
    const int r = tid >> 1, hf = tid & 1;
    bf16x8 rowv[16];
#pragma unroll
    for (int j = 0; j < 16; ++j) rowv[j] = *(const bf16x8*)&tile[r * TS + j * 8];
    float ss = 0.f;
#pragma unroll
    for (int j = 0; j < 16; ++j)
#pragma unroll
      for (int e = 0; e < 8; ++e) { const float f = (float)rowv[j][e]; ss += f * f; }
    const float sc = rsqrtf(ss * (1.0f / 128.0f) + 1e-6f) * osc;
    const int p = pos[bm + r];
    const float* rp = rope + p * 128;
    bf16_t obuf[64];
#pragma unroll
    for (int g = 0; g < 8; ++g) {
#pragma unroll
      for (int e = 0; e < 8; ++e) {
        const int i = g * 8 + e;
        const float2 cs = *(const float2*)(rp + 2 * i);
        const float nlo = (float)rowv[i >> 3][i & 7] * sc * nwp[i];
        const float nhi = (float)rowv[8 + (i >> 3)][i & 7] * sc * nwp[64 + i];
        obuf[i] = (bf16_t)(hf ? (nhi * cs.x + nlo * cs.y) : (nlo * cs.x - nhi * cs.y));
      }
    }
    bf16_t* op = outp + (long)(bm + r) * HD + hf * 64;
#pragma unroll
    for (int g = 0; g < 8; ++g) *(bf16x8*)(op + g * 8) = *(const bf16x8*)&obuf[g * 8];
  } else {  // ---- V head: transposed write [hk][d][s] ----
    const int hk = (bn - 5120) >> 7;
    const int d = tid & 127, shalf = tid >> 7;
    bf16_t* vp = Vb + ((long)hk * HD + d) * SEQL + bm + shalf * 64;
#pragma unroll
    for (int grp = 0; grp < 8; ++grp) {
      bf16x8 t;
#pragma unroll
      for (int e = 0; e < 8; ++e) t[e] = tile[(shalf * 64 + grp * 8 + e) * TS + d];
      *(bf16x8*)(vp + grp * 8) = t;
    }
  }
}

// ---------------- plain NT GEMM (O-projection): C[M,N] = A @ B^T, fp32 out ---
template <typename CT>
__global__ __launch_bounds__(256, 3) void gemm_bt_kernel(const bf16_t* __restrict__ A,
                                                         const bf16_t* __restrict__ B,
                                                         CT* __restrict__ C,
                                                         int N, int K, int npanel) {
  __shared__ bf16_t lA[128 * 64];
  __shared__ bf16_t lB[128 * 64];
  const int tid = threadIdx.x;
  const int lin = blockIdx.x;
  const int xcd = lin & 7, idx = lin >> 3;
  const int bm = (idx & 15) * 128;
  const int bn = ((idx >> 4) + xcd * npanel) * 128;
  const int lane = tid & 63, wave = tid >> 6;
  const int wm = (wave >> 1) * 64, wn = (wave & 1) * 64;
  const int lr = lane & 15, quad = lane >> 4;

  f32x4 acc[4][4];
#pragma unroll
  for (int mi = 0; mi < 4; ++mi)
#pragma unroll
    for (int ni = 0; ni < 4; ++ni)
      acc[mi][ni] = (f32x4){0.f, 0.f, 0.f, 0.f};

  long soff[4];
#pragma unroll
  for (int c = 0; c < 4; ++c) {
    const int s = tid + 256 * c;
    soff[c] = (long)(s >> 3) * K + (((s & 7) ^ ((s >> 3) & 7)) << 3);
  }
  const bf16_t* Abase = A + (long)bm * K;
  const bf16_t* Bbase = B + (long)bn * K;

  for (int k0 = 0; k0 < K; k0 += 64) {
    __syncthreads();
#pragma unroll
    for (int c = 0; c < 4; ++c) {
      gl2lds16(Abase + soff[c] + k0, lA + (tid + 256 * c) * 8);
      gl2lds16(Bbase + soff[c] + k0, lB + (tid + 256 * c) * 8);
    }
    __syncthreads();
#pragma unroll
    for (int ks = 0; ks < 2; ++ks) {
      bf16x8 af[4], bfr[4];
#pragma unroll
      for (int mi = 0; mi < 4; ++mi)
        af[mi] = *(const bf16x8*)&lA[(wm + mi * 16 + lr) * 64 + ((((ks << 2) | quad) ^ (lr & 7)) << 3)];
#pragma unroll
      for (int ni = 0; ni < 4; ++ni)
        bfr[ni] = *(const bf16x8*)&lB[(wn + ni * 16 + lr) * 64 + ((((ks << 2) | quad) ^ (lr & 7)) << 3)];
#pragma unroll
      for (int mi = 0; mi < 4; ++mi)
#pragma unroll
        for (int ni = 0; ni < 4; ++ni)
          acc[mi][ni] = __builtin_amdgcn_mfma_f32_16x16x32_bf16(af[mi], bfr[ni], acc[mi][ni], 0, 0, 0);
    }
  }

#pragma unroll
  for (int mi = 0; mi < 4; ++mi) {
    const int row = bm + wm + mi * 16 + quad * 4;
#pragma unroll
    for (int ni = 0; ni < 4; ++ni) {
      const int col = bn + wn + ni * 16 + lr;
      CT* cp = C + (long)row * N + col;
#pragma unroll
      for (int r = 0; r < 4; ++r) cp[(long)r * N] = (CT)acc[mi][ni][r];
    }
  }
}

// ---------------- flash attention, block-diag causal, FIXED-RANGE softmax ----
// RMSNorm bounds |score| <= 0.0884*128 = 11.32 -> exp2(s) can't overflow fp32;
// scale*log2e pre-folded into Q. Row-sum l via 16 ones-rows appended to V (di=8).
#define CK 64
#define PSTR 72
__global__ __launch_bounds__(256) void attn_kernel(const bf16_t* __restrict__ Q,
                                                   const bf16_t* __restrict__ Kt,
                                                   const bf16_t* __restrict__ Vt,
                                                   bf16_t* __restrict__ O) {
  __shared__ bf16_t lK[CK * 128];    // [kk][d]
  __shared__ bf16_t lV[144 * CK];    // [d][kk]; rows 128..143 = ones (l trick)
  __shared__ bf16_t lP[128 * PSTR];  // [m][kk]
  // complementary qb pairing: blocks i and i+256 share a CU -> qb sums to 3.
  const int lin = blockIdx.x;
  const int qb = (lin < 256) ? (3 - (lin & 1)) : (lin & 1);
  const int gh = (lin >> 1) & 127;
  const int h = gh & 31, g = gh >> 5;
  const int hk = h >> 2;
  const int tid = threadIdx.x, lane = tid & 63, wave = tid >> 6;
  const int lr = lane & 15, quad = lane >> 4;
  const int s_base = g * 512 + qb * 128;

  if (tid < 128) {
    bf16x8 one8;
#pragma unroll
    for (int j = 0; j < 8; ++j) one8[j] = (bf16_t)1.0f;
    *(bf16x8*)&lV[128 * CK + tid * 8] = one8;
  }

  bf16x8 qf[2][4];
  const bf16_t* Qp = Q + ((long)h * SEQL + s_base + wave * 32 + lr) * HD + quad * 8;
#pragma unroll
  for (int mi = 0; mi < 2; ++mi)
#pragma unroll
    for (int ks = 0; ks < 4; ++ks)
      qf[mi][ks] = *(const bf16x8*)(Qp + mi * 16 * HD + ks * 32);

  f32x4 oacc[2][9];
#pragma unroll
  for (int mi = 0; mi < 2; ++mi)
#pragma unroll
    for (int di = 0; di < 9; ++di) oacc[mi][di] = (f32x4){0.f, 0.f, 0.f, 0.f};

  const int nchunk = 2 * qb + 2;
  for (int c = 0; c < nchunk; ++c) {
    __syncthreads();
    {
      const bf16_t* Kg = Kt + ((long)hk * SEQL + g * 512 + c * CK) * HD;
      const bf16_t* Vg = Vt + (long)hk * HD * SEQL + g * 512 + c * CK;
#pragma unroll
      for (int cc = 0; cc < 4; ++cc) {
        const int i = tid + 256 * cc;
        gl2lds16(Kg + (long)(i >> 4) * HD + (i & 15) * 8, lK + i * 8);
        gl2lds16(Vg + (long)(i >> 3) * SEQL + (i & 7) * 8, lV + i * 8);
      }
    }
    __syncthreads();

    f32x4 sv[2][4];
#pragma unroll
    for (int mi = 0; mi < 2; ++mi)
#pragma unroll
      for (int ni = 0; ni < 4; ++ni) sv[mi][ni] = (f32x4){0.f, 0.f, 0.f, 0.f};
#pragma unroll
    for (int ks = 0; ks < 4; ++ks) {
#pragma unroll
      for (int ni = 0; ni < 4; ++ni) {
        const bf16x8 kf = *(const bf16x8*)&lK[(ni * 16 + lr) * 128 + ks * 32 + quad * 8];
        sv[0][ni] = __builtin_amdgcn_mfma_f32_16x16x32_bf16(qf[0][ks], kf, sv[0][ni], 0, 0, 0);
        sv[1][ni] = __builtin_amdgcn_mfma_f32_16x16x32_bf16(qf[1][ks], kf, sv[1][ni], 0, 0, 0);
      }
    }

    // p = exp2(s) (scale folded into Q), mask, straight to LDS in A-layout
#pragma unroll
    for (int mi = 0; mi < 2; ++mi)
#pragma unroll
      for (int ni = 0; ni < 4; ++ni)
#pragma unroll
        for (int r = 0; r < 4; ++r) {
          const int colseg = c * CK + ni * 16 + lr;
          const int rowseg = qb * 128 + wave * 32 + mi * 16 + quad * 4 + r;
          float p = exp2f(sv[mi][ni][r]);
          p = (colseg > rowseg) ? 0.f : p;
          lP[(wave * 32 + mi * 16 + quad * 4 + r) * PSTR + ni * 16 + lr] = (bf16_t)p;
        }
    __syncthreads();

    // O += P @ [V ; ones] (di=8 accumulates the row-sum l)
#pragma unroll
    for (int ks = 0; ks < 2; ++ks) {
      const bf16x8 pf0 = *(const bf16x8*)&lP[(wave * 32 + lr) * PSTR + ks * 32 + quad * 8];
      const bf16x8 pf1 = *(const bf16x8*)&lP[(wave * 32 + 16 + lr) * PSTR + ks * 32 + quad * 8];
#pragma unroll
      for (int di = 0; di < 9; ++di) {
        const bf16x8 vfr = *(const bf16x8*)&lV[(di * 16 + lr) * CK + ks * 32 + quad * 8];
        oacc[0][di] = __builtin_amdgcn_mfma_f32_16x16x32_bf16(pf0, vfr, oacc[0][di], 0, 0, 0);
        oacc[1][di] = __builtin_amdgcn_mfma_f32_16x16x32_bf16(pf1, vfr, oacc[1][di], 0, 0, 0);
      }
    }
  }

  // epilogue: O[s][h*128+d] = oacc/l
#pragma unroll
  for (int mi = 0; mi < 2; ++mi)
#pragma unroll
    for (int r = 0; r < 4; ++r) {
      const float inv = 1.0f / oacc[mi][8][r];
      const int row = s_base + wave * 32 + mi * 16 + quad * 4 + r;
      bf16_t* opp = O + (long)row * DIMM + h * HD + lr;
#pragma unroll
      for (int di = 0; di < 8; ++di) opp[di * 16] = (bf16_t)(oacc[mi][di][r] * inv);
    }
}

// -----------------------------------------------------------------------------
extern "C" void kernel_launch(void* const* d_in, const int* in_sizes, int n_in,
                              void* d_out, int out_size, void* d_ws, size_t ws_size,
                              hipStream_t stream) {
  (void)in_sizes; (void)n_in; (void)out_size; (void)ws_size;
  const float* x    = (const float*)d_in[0];
  const float* wq   = (const float*)d_in[1];
  const float* wk   = (const float*)d_in[2];
  const float* wv   = (const float*)d_in[3];
  const float* wo   = (const float*)d_in[4];
  const float* qnw  = (const float*)d_in[5];
  const float* knw  = (const float*)d_in[6];
  const float* rope = (const float*)d_in[7];
  const int*   pos  = (const int*)d_in[8];
  float* out = (float*)d_out;

  char* ws = (char*)d_ws;
  size_t off = 0;
  auto alloc = [&](size_t b) { char* p = ws + off; off += (b + 255) & ~(size_t)255; return p; };
  // first five allocations must stay contiguous (cvt5 writes them as one region)
  bf16_t* xb    = (bf16_t*)alloc((size_t)SEQL * DIMM * 2);          // 16 MiB
  bf16_t* wqkvb = (bf16_t*)alloc((size_t)DIMM * DIMM * 2);          // wq part, 32 MiB
  alloc((size_t)NKV * HD * DIMM * 2);                               // wk part (contiguous)
  alloc((size_t)NKV * HD * DIMM * 2);                               // wv part (contiguous)
  bf16_t* wob   = (bf16_t*)alloc((size_t)DIMM * DIMM * 2);          // 32 MiB
  // fresh space for Q/K/V (must NOT alias wqkv: epilogue writes overlap GEMM reads)
  bf16_t* Qb    = (bf16_t*)alloc((size_t)NH * SEQL * HD * 2);       // 16 MiB
  bf16_t* Kb    = (bf16_t*)alloc((size_t)NKV * SEQL * HD * 2);      // 4 MiB
  bf16_t* Vb    = (bf16_t*)alloc((size_t)NKV * SEQL * HD * 2);      // 4 MiB
  bf16_t* attnb = xb;  // [2048][4096], xb dead after QKV GEMM

  // 1) convert all inputs to bf16
  cvt5_kernel<<<dim3(12288), 256, 0, stream>>>(x, wq, wk, wv, wo, xb);
  // 2) fused QKV projection + RMSNorm + RoPE + V-transpose
  gemm_qkv_kernel<<<dim3(768), 256, 0, stream>>>(xb, wqkvb, qnw, knw, rope, pos, Qb, Kb, Vb);
  // 3) attention (512 blocks, complementary-qb pairing)
  attn_kernel<<<dim3(512), 256, 0, stream>>>(Qb, Kb, Vb, attnb);
  // 4) output projection -> fp32 d_out
  gemm_bt_kernel<float><<<dim3(512), 256, 0, stream>>>(attnb, wob, out, DIMM, DIMM, 4);
}